// Round 1
// baseline (24.232 us; speedup 1.0000x reference)
//
#include <hip/hip_runtime.h>

#define IN_DIM 10
#define OUT_DIM 3
#define BLOCK 256
#define ROWS_PER_BLOCK 512   // each thread handles local rows t and t+256

__global__ __launch_bounds__(BLOCK) void simnet_fused(
    const float* __restrict__ x,
    const float* __restrict__ W,
    const float* __restrict__ M,
    float* __restrict__ out,
    long long batch)
{
    __shared__ float s_x[ROWS_PER_BLOCK * IN_DIM];   // 5120 floats = 20 KB
    __shared__ float s_proj[OUT_DIM * IN_DIM];       // 30 floats

    const int t = threadIdx.x;
    const long long row0 = (long long)blockIdx.x * ROWS_PER_BLOCK;
    const long long total_in = batch * IN_DIM;

    // ---- thread 0: M^-1 (adjugate) and proj = M^-1 @ W into LDS ----
    if (t == 0) {
        const float a = M[0], b = M[1], c = M[2];
        const float d = M[3], e = M[4], f_ = M[5];
        const float g = M[6], h = M[7], i_ = M[8];
        const float A =  (e * i_ - f_ * h);
        const float B = -(d * i_ - f_ * g);
        const float C =  (d * h  - e  * g);
        const float det = a * A + b * B + c * C;
        float inv[3][3];
        // torch.isclose(det, 0, rtol=1e-5, atol=1e-8) -> |det| <= 1e-8
        if (fabsf(det) <= 1e-8f) {
            const float qn = __builtin_nanf("");
            #pragma unroll
            for (int o = 0; o < 3; ++o)
                #pragma unroll
                for (int k = 0; k < 3; ++k) inv[o][k] = qn;
        } else {
            const float r = 1.0f / det;
            inv[0][0] = A * r;
            inv[0][1] = (c * h  - b * i_) * r;
            inv[0][2] = (b * f_ - c * e ) * r;
            inv[1][0] = B * r;
            inv[1][1] = (a * i_ - c * g ) * r;
            inv[1][2] = (c * d  - a * f_) * r;
            inv[2][0] = C * r;
            inv[2][1] = (b * g  - a * h ) * r;
            inv[2][2] = (a * e  - b * d ) * r;
        }
        #pragma unroll
        for (int o = 0; o < OUT_DIM; ++o)
            #pragma unroll
            for (int j = 0; j < IN_DIM; ++j)
                s_proj[o * IN_DIM + j] = inv[o][0] * W[0 * IN_DIM + j]
                                       + inv[o][1] * W[1 * IN_DIM + j]
                                       + inv[o][2] * W[2 * IN_DIM + j];
    }

    // ---- coalesced input staging: 1280 float4 per block, 5 per thread ----
    {
        const long long base = row0 * IN_DIM;
        #pragma unroll
        for (int k = 0; k < 5; ++k) {
            const long long f = base + (long long)(k * BLOCK + t) * 4;
            float4 v = make_float4(0.f, 0.f, 0.f, 0.f);
            if (f + 4 <= total_in) {
                v = *reinterpret_cast<const float4*>(x + f);
            } else if (f < total_in) {
                const float* p = x + f;
                const int n = (int)(total_in - f);
                v.x = p[0];
                if (n > 1) v.y = p[1];
                if (n > 2) v.z = p[2];
            }
            *reinterpret_cast<float4*>(&s_x[(k * BLOCK + t) * 4]) = v;
        }
    }
    __syncthreads();

    // ---- compute: each thread does 2 rows x (10 -> 3) ----
    float pj[OUT_DIM][IN_DIM];
    #pragma unroll
    for (int o = 0; o < OUT_DIM; ++o)
        #pragma unroll
        for (int j = 0; j < IN_DIM; ++j)
            pj[o][j] = s_proj[o * IN_DIM + j];   // broadcast reads, conflict-free

    float acc[2][OUT_DIM];
    #pragma unroll
    for (int r = 0; r < 2; ++r) {
        const int lr = t + r * BLOCK;
        float xv[IN_DIM];
        #pragma unroll
        for (int j = 0; j < IN_DIM; ++j) xv[j] = s_x[lr * IN_DIM + j];
        #pragma unroll
        for (int o = 0; o < OUT_DIM; ++o) {
            float s = 0.f;
            #pragma unroll
            for (int j = 0; j < IN_DIM; ++j) s = fmaf(xv[j], pj[o][j], s);
            acc[r][o] = s;
        }
    }
    __syncthreads();   // everyone done reading s_x before reuse

    // ---- stage outputs into LDS for coalesced float4 stores ----
    #pragma unroll
    for (int r = 0; r < 2; ++r) {
        const int lr = t + r * BLOCK;
        #pragma unroll
        for (int o = 0; o < OUT_DIM; ++o)
            s_x[lr * OUT_DIM + o] = acc[r][o];
    }
    __syncthreads();

    const long long out_base = row0 * OUT_DIM;
    const long long total_out = batch * OUT_DIM;
    #pragma unroll
    for (int k = 0; k < 2; ++k) {
        const int idx = k * BLOCK + t;
        if (idx < (ROWS_PER_BLOCK * OUT_DIM) / 4) {      // 384 float4 per block
            const long long f = out_base + (long long)idx * 4;
            if (f + 4 <= total_out) {
                *reinterpret_cast<float4*>(out + f) =
                    *reinterpret_cast<const float4*>(&s_x[idx * 4]);
            } else if (f < total_out) {
                const int n = (int)(total_out - f);
                for (int j = 0; j < n; ++j) out[f + j] = s_x[idx * 4 + j];
            }
        }
    }
}

extern "C" void kernel_launch(void* const* d_in, const int* in_sizes, int n_in,
                              void* d_out, int out_size, void* d_ws, size_t ws_size,
                              hipStream_t stream) {
    const float* x = (const float*)d_in[0];
    const float* W = (const float*)d_in[1];
    const float* M = (const float*)d_in[2];
    float* out = (float*)d_out;
    const long long batch = (long long)in_sizes[0] / IN_DIM;
    const int grid = (int)((batch + ROWS_PER_BLOCK - 1) / ROWS_PER_BLOCK);
    simnet_fused<<<grid, BLOCK, 0, stream>>>(x, W, M, out, batch);
}